// Round 1
// baseline (282.187 us; speedup 1.0000x reference)
//
#include <hip/hip_runtime.h>

#define N_T 256
#define N_B 8192

__global__ __launch_bounds__(256) void qlstm_pre(
    const float* __restrict__ x,
    const float* __restrict__ Wf, const float* __restrict__ bf,
    const float* __restrict__ Wi, const float* __restrict__ bi,
    const float* __restrict__ Wu, const float* __restrict__ bu,
    const float* __restrict__ Wo, const float* __restrict__ bo,
    const float* __restrict__ thf, const float* __restrict__ thi,
    const float* __restrict__ thu, const float* __restrict__ tho,
    float* __restrict__ pre, int total)
{
    __shared__ float sW[16][32];
    __shared__ float sB[16];
    int tid = threadIdx.x;
    for (int k = tid; k < 512; k += 256) {
        int u = k >> 5, j = k & 31;
        int w = u >> 2, g = u & 3;
        const float* Wg = (g == 0) ? Wf : (g == 1) ? Wi : (g == 2) ? Wu : Wo;
        sW[u][j] = Wg[w * 36 + j];
    }
    if (tid < 16) {
        int u = tid, w = u >> 2, g = u & 3;
        const float* bg = (g == 0) ? bf : (g == 1) ? bi : (g == 2) ? bu : bo;
        const float* tg = (g == 0) ? thf : (g == 1) ? thi : (g == 2) ? thu : tho;
        sB[u] = bg[w] + tg[w];
    }
    __syncthreads();

    int idx = blockIdx.x * 256 + tid;
    if (idx >= total) return;

    const float4* xr = (const float4*)(x + (size_t)idx * 32);
    float4 xv[8];
#pragma unroll
    for (int k = 0; k < 8; ++k) xv[k] = xr[k];

    float acc[16];
#pragma unroll
    for (int u = 0; u < 16; ++u) {
        float a = sB[u];
        const float4* wr = (const float4*)(&sW[u][0]);
#pragma unroll
        for (int k = 0; k < 8; ++k) {
            float4 wv = wr[k];
            a += wv.x * xv[k].x + wv.y * xv[k].y + wv.z * xv[k].z + wv.w * xv[k].w;
        }
        acc[u] = a;
    }

    float4* pr = (float4*)(pre + (size_t)idx * 16);
#pragma unroll
    for (int k = 0; k < 4; ++k)
        pr[k] = make_float4(acc[4*k], acc[4*k+1], acc[4*k+2], acc[4*k+3]);
}

__device__ __forceinline__ float fast_sigmoid(float z) {
    return __builtin_amdgcn_rcpf(1.0f + __expf(-z));
}
__device__ __forceinline__ float fast_tanh(float z) {
    float e = __expf(2.0f * z);
    return 1.0f - 2.0f * __builtin_amdgcn_rcpf(e + 1.0f);
}
__device__ __forceinline__ float prodsel(float c0, float c1, float c2, float c3, int w) {
    float t01   = c0 * c1;
    float t012  = t01 * c2;
    float t0123 = t012 * c3;
    float t123  = c1 * (c2 * c3);
    return (w == 0) ? t123 : (w == 1) ? t01 : (w == 2) ? t012 : t0123;
}

__global__ __launch_bounds__(64) void qlstm_scan(
    const float* __restrict__ pre,
    const float* __restrict__ Wf, const float* __restrict__ Wi,
    const float* __restrict__ Wu, const float* __restrict__ Wo,
    const float* __restrict__ Wr, const float* __restrict__ br,
    float* __restrict__ stacked, float* __restrict__ regress,
    float* __restrict__ hT, float* __restrict__ cT,
    float* __restrict__ hs, float* __restrict__ cs,
    int steps, int toff, int first)
{
    int tid  = blockIdx.x * 64 + threadIdx.x;
    int b    = tid >> 2;
    int w    = tid & 3;
    int base = threadIdx.x & ~3;

    float whf0 = Wf[w*36+32], whf1 = Wf[w*36+33], whf2 = Wf[w*36+34], whf3 = Wf[w*36+35];
    float whi0 = Wi[w*36+32], whi1 = Wi[w*36+33], whi2 = Wi[w*36+34], whi3 = Wi[w*36+35];
    float whu0 = Wu[w*36+32], whu1 = Wu[w*36+33], whu2 = Wu[w*36+34], whu3 = Wu[w*36+35];
    float who0 = Wo[w*36+32], who1 = Wo[w*36+33], who2 = Wo[w*36+34], who3 = Wo[w*36+35];
    float wr0 = Wr[0], wr1 = Wr[1], wr2 = Wr[2], wr3 = Wr[3], brv = br[0];

    float h0, h1, h2, h3, cw;
    if (first) { h0 = h1 = h2 = h3 = 0.0f; cw = 0.0f; }
    else {
        h0 = hs[b*4+0]; h1 = hs[b*4+1]; h2 = hs[b*4+2]; h3 = hs[b*4+3];
        cw = cs[b*4+w];
    }

    const float4* prep = (const float4*)pre;
    float4 pf = prep[((size_t)b) * 4 + w];
    float hw = 0.0f;

    for (int t = 0; t < steps; ++t) {
        int tn = (t + 1 < steps) ? (t + 1) : t;
        float4 pn = prep[((size_t)tn * N_B + b) * 4 + w];

        float af = pf.x + whf0*h0 + whf1*h1 + whf2*h2 + whf3*h3;
        float ai = pf.y + whi0*h0 + whi1*h1 + whi2*h2 + whi3*h3;
        float au = pf.z + whu0*h0 + whu1*h1 + whu2*h2 + whu3*h3;
        float ao = pf.w + who0*h0 + who1*h1 + who2*h2 + who3*h3;

        float cfc = __cosf(af), cic = __cosf(ai), cuc = __cosf(au), coc = __cosf(ao);

        float cf0 = __shfl(cfc, base+0), cf1 = __shfl(cfc, base+1),
              cf2 = __shfl(cfc, base+2), cf3 = __shfl(cfc, base+3);
        float ci0 = __shfl(cic, base+0), ci1 = __shfl(cic, base+1),
              ci2 = __shfl(cic, base+2), ci3 = __shfl(cic, base+3);
        float cu0 = __shfl(cuc, base+0), cu1 = __shfl(cuc, base+1),
              cu2 = __shfl(cuc, base+2), cu3 = __shfl(cuc, base+3);
        float co0 = __shfl(coc, base+0), co1 = __shfl(coc, base+1),
              co2 = __shfl(coc, base+2), co3 = __shfl(coc, base+3);

        float qf = prodsel(cf0, cf1, cf2, cf3, w);
        float qi = prodsel(ci0, ci1, ci2, ci3, w);
        float qu = prodsel(cu0, cu1, cu2, cu3, w);
        float qo = prodsel(co0, co1, co2, co3, w);

        float fg = fast_sigmoid(qf);
        float ig = fast_sigmoid(qi);
        float gg = fast_tanh(qu);
        float og = fast_sigmoid(qo);

        cw = fg * cw + ig * gg;
        float tc = fast_tanh(cw);
        hw = og * tc;

        h0 = __shfl(hw, base+0); h1 = __shfl(hw, base+1);
        h2 = __shfl(hw, base+2); h3 = __shfl(hw, base+3);

        float reg = brv + wr0*h0 + wr1*h1 + wr2*h2 + wr3*h3;

        size_t tg = (size_t)(toff + t);
        stacked[(tg * N_B + b) * 4 + w] = hw;
        if (w == 0) regress[tg * N_B + b] = reg;

        pf = pn;
    }

    hs[b*4+w] = hw;  cs[b*4+w] = cw;
    hT[b*4+w] = hw;  cT[b*4+w] = cw;
}

extern "C" void kernel_launch(void* const* d_in, const int* in_sizes, int n_in,
                              void* d_out, int out_size, void* d_ws, size_t ws_size,
                              hipStream_t stream)
{
    (void)in_sizes; (void)n_in; (void)out_size;
    const float* x   = (const float*)d_in[0];
    const float* Wf  = (const float*)d_in[1];
    const float* bf_ = (const float*)d_in[2];
    const float* Wi  = (const float*)d_in[3];
    const float* bi_ = (const float*)d_in[4];
    const float* Wu  = (const float*)d_in[5];
    const float* bu_ = (const float*)d_in[6];
    const float* Wo  = (const float*)d_in[7];
    const float* bo_ = (const float*)d_in[8];
    const float* thf = (const float*)d_in[9];
    const float* thi = (const float*)d_in[10];
    const float* thu = (const float*)d_in[11];
    const float* tho = (const float*)d_in[12];
    const float* Wr  = (const float*)d_in[13];
    const float* br_ = (const float*)d_in[14];

    float* out     = (float*)d_out;
    float* stacked = out;                                   // T*B*4
    float* regress = out + (size_t)N_T * N_B * 4;           // T*B
    float* hT      = regress + (size_t)N_T * N_B;           // B*4
    float* cT      = hT + (size_t)N_B * 4;                  // B*4

    size_t stateBytes = (size_t)N_B * 8 * sizeof(float);
    int Tc = N_T;
    while (Tc > 1 && (size_t)Tc * N_B * 16 * sizeof(float) + stateBytes > ws_size)
        Tc >>= 1;

    float* pre = (float*)d_ws;
    float* hs  = pre + (size_t)Tc * N_B * 16;
    float* cs  = hs + (size_t)N_B * 4;

    for (int toff = 0; toff < N_T; toff += Tc) {
        int steps = (N_T - toff < Tc) ? (N_T - toff) : Tc;
        int total = steps * N_B;
        qlstm_pre<<<(total + 255) / 256, 256, 0, stream>>>(
            x + (size_t)toff * N_B * 32,
            Wf, bf_, Wi, bi_, Wu, bu_, Wo, bo_,
            thf, thi, thu, tho, pre, total);
        qlstm_scan<<<(N_B * 4) / 64, 64, 0, stream>>>(
            pre, Wf, Wi, Wu, Wo, Wr, br_,
            stacked, regress, hT, cT, hs, cs,
            steps, toff, toff == 0 ? 1 : 0);
    }
}